// Round 3
// baseline (558.805 us; speedup 1.0000x reference)
//
#include <hip/hip_runtime.h>

// 2-layer GCN collapsed to scalar per-node quantities.
// deg[d] = (# edges with dst==d) + 1 (self loop); dis = 1/sqrt(deg)
// s[d]   = dis[d] * ( sum_{e->d} x[src]*dis[src] + x[d]*dis[d] )
// g[d]   = sum_j relu(s[d]*W1[j] + b1[j]) * W2[j]
// out[d] = dis[d] * ( sum_{e->d} g[src]*dis[src] + g[d]*dis[d] ) + b2
//
// R2 counters: 3 edge-atomic passes dominate (19G atomics/s, VALUBusy 0.5%).
// R3 change: 8 edges/thread (MLP batching) + native fp32 atomics
// (unsafeAtomicAdd -> global_atomic_add_f32, avoids CAS loop).

#define EPT 8  // edges per thread

__device__ inline void atomic_add_f32(float* p, float v) {
#if defined(__HIP_PLATFORM_AMD__)
    unsafeAtomicAdd(p, v);   // native global_atomic_add_f32 (no CAS loop)
#else
    atomicAdd(p, v);
#endif
}

__global__ void degree_k(const int* __restrict__ dst, int E,
                         unsigned int* __restrict__ deg) {
    int i0 = (blockIdx.x * blockDim.x + threadIdx.x) * EPT;
    if (i0 + EPT <= E) {
        int4 a = *(const int4*)(dst + i0);
        int4 b = *(const int4*)(dst + i0 + 4);
        atomicAdd(&deg[a.x], 1u); atomicAdd(&deg[a.y], 1u);
        atomicAdd(&deg[a.z], 1u); atomicAdd(&deg[a.w], 1u);
        atomicAdd(&deg[b.x], 1u); atomicAdd(&deg[b.y], 1u);
        atomicAdd(&deg[b.z], 1u); atomicAdd(&deg[b.w], 1u);
    } else {
        for (int i = i0; i < E; i++) atomicAdd(&deg[dst[i]], 1u);
    }
}

__global__ void prep1_k(const float* __restrict__ x,
                        const unsigned int* __restrict__ deg,
                        float* __restrict__ dis, float* __restrict__ y, int N) {
    int i = blockIdx.x * blockDim.x + threadIdx.x;
    if (i < N) {
        float d = (float)(deg[i] + 1u);   // +1 self loop
        float r = 1.0f / sqrtf(d);
        dis[i] = r;
        y[i] = x[i] * r;
    }
}

__global__ void scatter_k(const int* __restrict__ src,
                          const int* __restrict__ dst,
                          const float* __restrict__ val,
                          float* __restrict__ acc, int E) {
    int i0 = (blockIdx.x * blockDim.x + threadIdx.x) * EPT;
    if (i0 + EPT <= E) {
        int4 sa = *(const int4*)(src + i0);
        int4 sb = *(const int4*)(src + i0 + 4);
        int4 da = *(const int4*)(dst + i0);
        int4 db = *(const int4*)(dst + i0 + 4);
        // issue all 8 gathers before any atomic (8-way MLP)
        float v0 = val[sa.x], v1 = val[sa.y], v2 = val[sa.z], v3 = val[sa.w];
        float v4 = val[sb.x], v5 = val[sb.y], v6 = val[sb.z], v7 = val[sb.w];
        atomic_add_f32(&acc[da.x], v0); atomic_add_f32(&acc[da.y], v1);
        atomic_add_f32(&acc[da.z], v2); atomic_add_f32(&acc[da.w], v3);
        atomic_add_f32(&acc[db.x], v4); atomic_add_f32(&acc[db.y], v5);
        atomic_add_f32(&acc[db.z], v6); atomic_add_f32(&acc[db.w], v7);
    } else {
        for (int i = i0; i < E; i++) atomic_add_f32(&acc[dst[i]], val[src[i]]);
    }
}

__global__ void prep2_k(const float* __restrict__ dis,
                        const float* __restrict__ y,
                        const float* __restrict__ t,
                        const float* __restrict__ W1,
                        const float* __restrict__ b1,
                        const float* __restrict__ W2,
                        float* __restrict__ z, int N, int H) {
    extern __shared__ float smem[];
    float* sW1 = smem;
    float* sb1 = smem + H;
    float* sW2 = smem + 2 * H;
    for (int j = threadIdx.x; j < H; j += blockDim.x) {
        sW1[j] = W1[j];
        sb1[j] = b1[j];
        sW2[j] = W2[j];
    }
    __syncthreads();
    int i = blockIdx.x * blockDim.x + threadIdx.x;
    if (i >= N) return;
    float r = dis[i];
    float s = r * (t[i] + y[i]);   // layer-1 pre-activation scale
    float g = 0.0f;
    #pragma unroll 8
    for (int j = 0; j < H; j++) {
        float h = s * sW1[j] + sb1[j];
        h = h > 0.0f ? h : 0.0f;   // relu
        g += h * sW2[j];
    }
    z[i] = g * r;   // pre-scaled message for layer 2
}

__global__ void final_k(const float* __restrict__ dis,
                        const float* __restrict__ z,
                        const float* __restrict__ u,
                        const float* __restrict__ b2,
                        float* __restrict__ out, int N) {
    int i = blockIdx.x * blockDim.x + threadIdx.x;
    if (i < N) {
        out[i] = dis[i] * (u[i] + z[i]) + b2[0];
    }
}

extern "C" void kernel_launch(void* const* d_in, const int* in_sizes, int n_in,
                              void* d_out, int out_size, void* d_ws, size_t ws_size,
                              hipStream_t stream) {
    const float* x   = (const float*)d_in[0];
    const int*   ei  = (const int*)d_in[1];     // int32 (JAX x64-off)
    const float* W1  = (const float*)d_in[2];
    const float* b1  = (const float*)d_in[3];
    const float* W2  = (const float*)d_in[4];
    const float* b2  = (const float*)d_in[5];
    float*       out = (float*)d_out;

    const int N = in_sizes[0];        // 100000
    const int E = in_sizes[1] / 2;    // 3200000
    const int H = in_sizes[2];        // 256

    const int* srcp = ei;             // edge_index[0]
    const int* dstp = ei + E;         // edge_index[1]

    // workspace: [deg u32: N][t f32: N][u f32: N][dis f32: N][y f32: N][z f32: N]
    float* ws = (float*)d_ws;
    unsigned int* deg = (unsigned int*)ws;
    float* t   = ws + (size_t)N;
    float* u   = ws + (size_t)2 * N;
    float* dis = ws + (size_t)3 * N;
    float* y   = ws + (size_t)4 * N;
    float* z   = ws + (size_t)5 * N;

    hipMemsetAsync(d_ws, 0, (size_t)3 * N * sizeof(float), stream);

    const int TB = 256;
    const int nThreadsE = (E + EPT - 1) / EPT;
    const int gE = (nThreadsE + TB - 1) / TB;
    const int gN = (N + TB - 1) / TB;

    degree_k<<<gE, TB, 0, stream>>>(dstp, E, deg);
    prep1_k<<<gN, TB, 0, stream>>>(x, deg, dis, y, N);
    scatter_k<<<gE, TB, 0, stream>>>(srcp, dstp, y, t, E);
    prep2_k<<<gN, TB, (size_t)3 * H * sizeof(float), stream>>>(dis, y, t, W1, b1, W2, z, N, H);
    scatter_k<<<gE, TB, 0, stream>>>(srcp, dstp, z, u, E);
    final_k<<<gN, TB, 0, stream>>>(dis, z, u, b2, out, N);
}

// Round 4
// 234.893 us; speedup vs baseline: 2.3790x; 2.3790x over previous
//
#include <hip/hip_runtime.h>

// 2-layer GCN collapsed to scalar per-node quantities (see R2).
// R4: the R2/R3 counters showed every global atomic writes through to the
// memory side as a 32B granule (WRITE_SIZE == E*32B, ~19G atomics/s wall).
// This version eliminates ALL global atomics: edges are partitioned by dst
// into buckets of S=128 nodes via hist->scan->exact-placement (no atomics),
// then degree / sum(y) / sum(z) are LDS-accumulated per bucket and each
// output element is written exactly once.

#define SBITS 7
#define S 128          // nodes per bucket (dstlocal fits u8)
#define NA 256         // phase-A blocks == hist rows (must equal TB)
#define TB 256

__device__ inline unsigned exscan256(unsigned v, unsigned* tmp) {
    int t = threadIdx.x;
    tmp[t] = v;
    __syncthreads();
    for (int off = 1; off < 256; off <<= 1) {
        unsigned a = (t >= off) ? tmp[t - off] : 0u;
        __syncthreads();
        tmp[t] += a;
        __syncthreads();
    }
    return tmp[t] - v;   // exclusive
}

// A1: per-block histogram of dst buckets. hist[blk][b], blk in [0,NA)
__global__ void hist_k(const int* __restrict__ dst, int E, int NB,
                       unsigned* __restrict__ hist) {
    extern __shared__ unsigned h[];
    for (int i = threadIdx.x; i < NB; i += TB) h[i] = 0u;
    __syncthreads();
    int CH = (E + NA - 1) / NA;
    int s = blockIdx.x * CH;
    int e = min(s + CH, E);
    for (int j = s + threadIdx.x; j < e; j += TB)
        atomicAdd(&h[((unsigned)dst[j]) >> SBITS], 1u);   // LDS atomic
    __syncthreads();
    unsigned* out = hist + (size_t)blockIdx.x * NB;
    for (int i = threadIdx.x; i < NB; i += TB) out[i] = h[i];
}

// A2a: column sums (bucket totals). grid = NB blocks.
__global__ void colsum_k(const unsigned* __restrict__ hist, int NB,
                         unsigned* __restrict__ colsum) {
    __shared__ unsigned tmp[TB];
    int b = blockIdx.x;
    tmp[threadIdx.x] = hist[(size_t)threadIdx.x * NB + b];
    __syncthreads();
    for (int off = 128; off > 0; off >>= 1) {
        if (threadIdx.x < off) tmp[threadIdx.x] += tmp[threadIdx.x + off];
        __syncthreads();
    }
    if (threadIdx.x == 0) colsum[b] = tmp[0];
}

// A2b: exclusive scan of bucket totals -> bucketStart. 1 block, NB<=1024.
__global__ void scanb_k(const unsigned* __restrict__ colsum, int NB,
                        unsigned* __restrict__ bstart) {
    __shared__ unsigned tmp[TB];
    int t = threadIdx.x;
    unsigned pre[4]; unsigned run = 0;
    for (int j = 0; j < 4; j++) {
        int i = t * 4 + j;
        pre[j] = run;
        run += (i < NB) ? colsum[i] : 0u;
    }
    unsigned base = exscan256(run, tmp);
    for (int j = 0; j < 4; j++) {
        int i = t * 4 + j;
        if (i < NB) bstart[i] = base + pre[j];
    }
}

// A2c: per-(block,bucket) placement base = bstart[b] + scan_k hist[k][b].
__global__ void base_k(const unsigned* __restrict__ hist,
                       const unsigned* __restrict__ bstart, int NB,
                       unsigned* __restrict__ base) {
    __shared__ unsigned tmp[TB];
    int b = blockIdx.x;
    unsigned v = hist[(size_t)threadIdx.x * NB + b];
    unsigned ex = exscan256(v, tmp);
    base[(size_t)threadIdx.x * NB + b] = bstart[b] + ex;
}

// A3: scatter edges to exact bucket-major positions (LDS cursors only).
__global__ void part_k(const int* __restrict__ src, const int* __restrict__ dst,
                       int E, int NB,
                       const unsigned* __restrict__ base,
                       unsigned* __restrict__ srcB,
                       unsigned char* __restrict__ dlocB) {
    extern __shared__ unsigned cur[];
    const unsigned* mybase = base + (size_t)blockIdx.x * NB;
    for (int i = threadIdx.x; i < NB; i += TB) cur[i] = mybase[i];
    __syncthreads();
    int CH = (E + NA - 1) / NA;
    int s = blockIdx.x * CH;
    int e = min(s + CH, E);
    for (int j = s + threadIdx.x; j < e; j += TB) {
        unsigned d = (unsigned)dst[j];
        unsigned b = d >> SBITS;
        unsigned pos = atomicAdd(&cur[b], 1u);   // LDS atomic
        srcB[pos] = (unsigned)src[j];
        dlocB[pos] = (unsigned char)(d & (S - 1));
    }
}

// B1: per-bucket degree count -> dis = 1/sqrt(deg+1), y = x*dis.
__global__ void degdis_k(const unsigned char* __restrict__ dlocB,
                         const unsigned* __restrict__ bstart,
                         const unsigned* __restrict__ colsum,
                         const float* __restrict__ x, int N,
                         float* __restrict__ dis, float* __restrict__ y) {
    __shared__ unsigned acc[S];
    if (threadIdx.x < S) acc[threadIdx.x] = 0u;
    __syncthreads();
    int b = blockIdx.x;
    unsigned st = bstart[b], cnt = colsum[b];
    for (unsigned j = threadIdx.x; j < cnt; j += TB)
        atomicAdd(&acc[dlocB[st + j]], 1u);
    __syncthreads();
    if (threadIdx.x < S) {
        int node = b * S + threadIdx.x;
        if (node < N) {
            float r = 1.0f / sqrtf((float)(acc[threadIdx.x] + 1u));
            dis[node] = r;
            y[node] = x[node] * r;
        }
    }
}

__device__ inline void lds_addf(float* p, float v) {
    __hip_atomic_fetch_add(p, v, __ATOMIC_RELAXED, __HIP_MEMORY_SCOPE_WORKGROUP);
}

// B2: outv[d] = sum over bucket edges of val[src]
__global__ void gacc_k(const unsigned* __restrict__ srcB,
                       const unsigned char* __restrict__ dlocB,
                       const unsigned* __restrict__ bstart,
                       const unsigned* __restrict__ colsum,
                       const float* __restrict__ val, int N,
                       float* __restrict__ outv) {
    __shared__ float acc[S];
    if (threadIdx.x < S) acc[threadIdx.x] = 0.0f;
    __syncthreads();
    int b = blockIdx.x;
    unsigned st = bstart[b], cnt = colsum[b];
    unsigned j = threadIdx.x;
    for (; j + TB < cnt; j += 2 * TB) {
        unsigned s0 = srcB[st + j], s1 = srcB[st + j + TB];
        unsigned d0 = dlocB[st + j], d1 = dlocB[st + j + TB];
        float v0 = val[s0], v1 = val[s1];
        lds_addf(&acc[d0], v0);
        lds_addf(&acc[d1], v1);
    }
    for (; j < cnt; j += TB)
        lds_addf(&acc[dlocB[st + j]], val[srcB[st + j]]);
    __syncthreads();
    if (threadIdx.x < S) {
        int node = b * S + threadIdx.x;
        if (node < N) outv[node] = acc[threadIdx.x];
    }
}

// B3: fused second aggregation + epilogue: out = dis*(sum + z) + b2
__global__ void gaccfin_k(const unsigned* __restrict__ srcB,
                          const unsigned char* __restrict__ dlocB,
                          const unsigned* __restrict__ bstart,
                          const unsigned* __restrict__ colsum,
                          const float* __restrict__ z,
                          const float* __restrict__ dis,
                          const float* __restrict__ b2, int N,
                          float* __restrict__ out) {
    __shared__ float acc[S];
    if (threadIdx.x < S) acc[threadIdx.x] = 0.0f;
    __syncthreads();
    int b = blockIdx.x;
    unsigned st = bstart[b], cnt = colsum[b];
    unsigned j = threadIdx.x;
    for (; j + TB < cnt; j += 2 * TB) {
        unsigned s0 = srcB[st + j], s1 = srcB[st + j + TB];
        unsigned d0 = dlocB[st + j], d1 = dlocB[st + j + TB];
        float v0 = z[s0], v1 = z[s1];
        lds_addf(&acc[d0], v0);
        lds_addf(&acc[d1], v1);
    }
    for (; j < cnt; j += TB)
        lds_addf(&acc[dlocB[st + j]], z[srcB[st + j]]);
    __syncthreads();
    if (threadIdx.x < S) {
        int node = b * S + threadIdx.x;
        if (node < N)
            out[node] = dis[node] * (acc[threadIdx.x] + z[node]) + b2[0];
    }
}

// per-node MLP: z = dis * sum_j relu(s*W1[j]+b1[j])*W2[j], s = dis*(t+y)
__global__ void prep2_k(const float* __restrict__ dis,
                        const float* __restrict__ y,
                        const float* __restrict__ t,
                        const float* __restrict__ W1,
                        const float* __restrict__ b1,
                        const float* __restrict__ W2,
                        float* __restrict__ z, int N, int H) {
    extern __shared__ float smem[];
    float* sW1 = smem;
    float* sb1 = smem + H;
    float* sW2 = smem + 2 * H;
    for (int j = threadIdx.x; j < H; j += blockDim.x) {
        sW1[j] = W1[j];
        sb1[j] = b1[j];
        sW2[j] = W2[j];
    }
    __syncthreads();
    int i = blockIdx.x * blockDim.x + threadIdx.x;
    if (i >= N) return;
    float r = dis[i];
    float s = r * (t[i] + y[i]);
    float g = 0.0f;
    #pragma unroll 8
    for (int j = 0; j < H; j++) {
        float h = s * sW1[j] + sb1[j];
        h = h > 0.0f ? h : 0.0f;
        g += h * sW2[j];
    }
    z[i] = g * r;
}

extern "C" void kernel_launch(void* const* d_in, const int* in_sizes, int n_in,
                              void* d_out, int out_size, void* d_ws, size_t ws_size,
                              hipStream_t stream) {
    const float* x   = (const float*)d_in[0];
    const int*   ei  = (const int*)d_in[1];     // int32 (JAX x64-off)
    const float* W1  = (const float*)d_in[2];
    const float* b1  = (const float*)d_in[3];
    const float* W2  = (const float*)d_in[4];
    const float* b2  = (const float*)d_in[5];
    float*       out = (float*)d_out;

    const int N = in_sizes[0];        // 100000
    const int E = in_sizes[1] / 2;    // 3200000
    const int H = in_sizes[2];        // 256
    const int NB = (N + S - 1) / S;   // 782 buckets

    const int* srcp = ei;
    const int* dstp = ei + E;

    // workspace layout (u32 units)
    unsigned* W = (unsigned*)d_ws;
    float*    dis    = (float*)(W);
    float*    y      = (float*)(W + (size_t)N);
    float*    z      = (float*)(W + (size_t)2 * N);
    float*    t      = (float*)(W + (size_t)3 * N);
    unsigned* colsum = W + (size_t)4 * N;
    unsigned* bstart = colsum + NB;
    unsigned* hist   = bstart + NB;                    // NA*NB
    unsigned* base   = hist + (size_t)NA * NB;         // NA*NB
    unsigned* srcB   = base + (size_t)NA * NB;         // E
    unsigned char* dlocB = (unsigned char*)(srcB + (size_t)E);  // E bytes

    const size_t smemNB = (size_t)NB * sizeof(unsigned);
    const int gN = (N + TB - 1) / TB;

    hist_k  <<<NA, TB, smemNB, stream>>>(dstp, E, NB, hist);
    colsum_k<<<NB, TB, 0, stream>>>(hist, NB, colsum);
    scanb_k <<<1,  TB, 0, stream>>>(colsum, NB, bstart);
    base_k  <<<NB, TB, 0, stream>>>(hist, bstart, NB, base);
    part_k  <<<NA, TB, smemNB, stream>>>(srcp, dstp, E, NB, base, srcB, dlocB);
    degdis_k<<<NB, TB, 0, stream>>>(dlocB, bstart, colsum, x, N, dis, y);
    gacc_k  <<<NB, TB, 0, stream>>>(srcB, dlocB, bstart, colsum, y, N, t);
    prep2_k <<<gN, TB, (size_t)3 * H * sizeof(float), stream>>>(dis, y, t, W1, b1, W2, z, N, H);
    gaccfin_k<<<NB, TB, 0, stream>>>(srcB, dlocB, bstart, colsum, z, dis, b2, N, out);
}

// Round 5
// 194.557 us; speedup vs baseline: 2.8722x; 1.2073x over previous
//
#include <hip/hip_runtime.h>

// 2-layer GCN collapsed to scalar per-node quantities (verified R2):
//   dis = 1/sqrt(deg+1);  y = x*dis;  t[d] = sum_{e->d} y[src]
//   s = dis*(t+y);  z = dis * sum_j relu(s*W1[j]+b1[j])*W2[j]
//   out[d] = dis[d]*(sum_{e->d} z[src] + z[d]) + b2
//
// R4 counters: part_k WRITE_SIZE=150MB (32B granule per scattered 4B store).
// R5: coarse buckets (2048 nodes, NB=49), block-local tile sort in LDS so
// partition writes are coalesced runs (~42 u32), per-(tile,bucket) global
// cursor claim (no hist/scan kernels), 4B packed edge records
// (src | dloc<<17), sliced LDS aggregation with dense partials.

#define SB_BITS 11
#define SBK     2048          // nodes per bucket
#define MAXB    64            // LDS bound on bucket count (N <= 131072)
#define TBP     256           // part_k block size
#define NAP     512           // part_k grid
#define TPT     2048          // part_k tile (8 edges/thread)
#define RSL     16            // slices per bucket in aggregation
#define TBA     256           // aggregation block size

__device__ inline void lds_addf(float* p, float v) {
    __hip_atomic_fetch_add(p, v, __ATOMIC_RELAXED, __HIP_MEMORY_SCOPE_WORKGROUP);
}

// Partition: edges -> packedB[b*cap + pos], bucket-contiguous, coalesced.
__global__ __launch_bounds__(TBP) void part_k(
        const int* __restrict__ src, const int* __restrict__ dst, int E,
        int cap, unsigned* __restrict__ gcur, unsigned* __restrict__ packedB) {
    __shared__ unsigned sp[TPT];
    __shared__ unsigned char sbk[TPT];
    __shared__ unsigned hist[MAXB], scn[MAXB], cnt2[MAXB], gbase[MAXB];
    const int t = threadIdx.x;
    int CH = (E + (int)gridDim.x - 1) / (int)gridDim.x;
    int cs = blockIdx.x * CH;
    int ce = min(cs + CH, E);
    for (int ts = cs; ts < ce; ts += TPT) {
        int tcnt = min(TPT, ce - ts);
        if (t < MAXB) { hist[t] = 0u; cnt2[t] = 0u; }
        __syncthreads();
        unsigned es[8], ed[8];
        int nk = 0;
        #pragma unroll
        for (int k = 0; k < 8; k++) {
            int j = ts + t + k * TBP;
            if (j < ce) {
                es[k] = (unsigned)src[j];
                ed[k] = (unsigned)dst[j];
                atomicAdd(&hist[ed[k] >> SB_BITS], 1u);
                nk = k + 1;
            }
        }
        __syncthreads();
        if (t < MAXB) {
            unsigned h = hist[t];
            gbase[t] = h ? atomicAdd(&gcur[t], h) : 0u;   // global claim
            scn[t] = h;
        }
        __syncthreads();
        for (int off = 1; off < MAXB; off <<= 1) {        // inclusive scan
            unsigned v = 0u;
            if (t < MAXB && t >= off) v = scn[t - off];
            __syncthreads();
            if (t < MAXB) scn[t] += v;
            __syncthreads();
        }
        for (int k = 0; k < nk; k++) {                    // rank + stage sorted
            unsigned b = ed[k] >> SB_BITS;
            unsigned ex = scn[b] - hist[b];
            unsigned r = ex + atomicAdd(&cnt2[b], 1u);
            sp[r]  = es[k] | ((ed[k] & (SBK - 1u)) << 17);
            sbk[r] = (unsigned char)b;
        }
        __syncthreads();
        #pragma unroll
        for (int k = 0; k < 8; k++) {                     // coalesced write-out
            int j2 = t + k * TBP;
            if (j2 < tcnt) {
                unsigned b = sbk[j2];
                unsigned ex = scn[b] - hist[b];
                unsigned gpos = gbase[b] + (unsigned)j2 - ex;
                if (gpos < (unsigned)cap)                 // overflow guard
                    packedB[(size_t)b * cap + gpos] = sp[j2];
            }
        }
        __syncthreads();
    }
}

// Degree partials: grid NB*RSL, LDS u32 accumulator per bucket slice.
__global__ __launch_bounds__(TBA) void degp_k(
        const unsigned* __restrict__ packedB, const unsigned* __restrict__ gcur,
        int cap, int PLN, unsigned* __restrict__ dpart) {
    __shared__ unsigned acc[SBK];
    for (int i = threadIdx.x; i < SBK; i += TBA) acc[i] = 0u;
    __syncthreads();
    int b = blockIdx.x / RSL, r = blockIdx.x % RSL;
    unsigned cnt = min(gcur[b], (unsigned)cap);
    unsigned per = (cnt + RSL - 1) / RSL;
    unsigned s = r * per, e = min(s + per, cnt);
    const unsigned* p = packedB + (size_t)b * cap;
    for (unsigned j = s + threadIdx.x; j < e; j += TBA)
        atomicAdd(&acc[p[j] >> 17], 1u);
    __syncthreads();
    unsigned* o = dpart + (size_t)r * PLN + (size_t)b * SBK;
    for (int i = threadIdx.x; i < SBK; i += TBA) o[i] = acc[i];
}

// Float gather-accumulate partials (used for y-pass and z-pass).
__global__ __launch_bounds__(TBA) void gaccp_k(
        const unsigned* __restrict__ packedB, const unsigned* __restrict__ gcur,
        const float* __restrict__ val, int cap, int PLN,
        float* __restrict__ fpart) {
    __shared__ float acc[SBK];
    for (int i = threadIdx.x; i < SBK; i += TBA) acc[i] = 0.0f;
    __syncthreads();
    int b = blockIdx.x / RSL, r = blockIdx.x % RSL;
    unsigned cnt = min(gcur[b], (unsigned)cap);
    unsigned per = (cnt + RSL - 1) / RSL;
    unsigned s = r * per, e = min(s + per, cnt);
    const unsigned* p = packedB + (size_t)b * cap;
    for (unsigned j = s + threadIdx.x; j < e; j += TBA) {
        unsigned pk = p[j];
        lds_addf(&acc[pk >> 17], val[pk & 0x1FFFFu]);
    }
    __syncthreads();
    float* o = fpart + (size_t)r * PLN + (size_t)b * SBK;
    for (int i = threadIdx.x; i < SBK; i += TBA) o[i] = acc[i];
}

// deg-reduce + dis + y
__global__ void prep1_k(const unsigned* __restrict__ dpart,
                        const float* __restrict__ x, int N, int PLN,
                        float* __restrict__ dis, float* __restrict__ y) {
    int i = blockIdx.x * blockDim.x + threadIdx.x;
    if (i >= N) return;
    unsigned d = 1u;   // self loop
    #pragma unroll
    for (int r = 0; r < RSL; r++) d += dpart[(size_t)r * PLN + i];
    float rr = 1.0f / sqrtf((float)d);
    dis[i] = rr;
    y[i] = x[i] * rr;
}

// t-reduce + per-node MLP: z = dis * sum_j relu(s*W1[j]+b1[j])*W2[j]
__global__ void prep2_k(const float* __restrict__ tpart,
                        const float* __restrict__ dis,
                        const float* __restrict__ y,
                        const float* __restrict__ W1,
                        const float* __restrict__ b1,
                        const float* __restrict__ W2,
                        float* __restrict__ z, int N, int H, int PLN) {
    extern __shared__ float smem[];
    float* sW1 = smem;
    float* sb1 = smem + H;
    float* sW2 = smem + 2 * H;
    for (int j = threadIdx.x; j < H; j += blockDim.x) {
        sW1[j] = W1[j]; sb1[j] = b1[j]; sW2[j] = W2[j];
    }
    __syncthreads();
    int i = blockIdx.x * blockDim.x + threadIdx.x;
    if (i >= N) return;
    float tt = 0.0f;
    #pragma unroll
    for (int r = 0; r < RSL; r++) tt += tpart[(size_t)r * PLN + i];
    float rr = dis[i];
    float s = rr * (tt + y[i]);
    float g = 0.0f;
    #pragma unroll 8
    for (int j = 0; j < H; j++) {
        float h = s * sW1[j] + sb1[j];
        h = h > 0.0f ? h : 0.0f;
        g += h * sW2[j];
    }
    z[i] = g * rr;
}

// z-reduce + epilogue
__global__ void finout_k(const float* __restrict__ zpart,
                         const float* __restrict__ dis,
                         const float* __restrict__ z,
                         const float* __restrict__ b2, int N, int PLN,
                         float* __restrict__ out) {
    int i = blockIdx.x * blockDim.x + threadIdx.x;
    if (i >= N) return;
    float u = 0.0f;
    #pragma unroll
    for (int r = 0; r < RSL; r++) u += zpart[(size_t)r * PLN + i];
    out[i] = dis[i] * (u + z[i]) + b2[0];
}

extern "C" void kernel_launch(void* const* d_in, const int* in_sizes, int n_in,
                              void* d_out, int out_size, void* d_ws, size_t ws_size,
                              hipStream_t stream) {
    const float* x   = (const float*)d_in[0];
    const int*   ei  = (const int*)d_in[1];     // int32 (JAX x64-off)
    const float* W1  = (const float*)d_in[2];
    const float* b1  = (const float*)d_in[3];
    const float* W2  = (const float*)d_in[4];
    const float* b2  = (const float*)d_in[5];
    float*       out = (float*)d_out;

    const int N = in_sizes[0];        // 100000
    const int E = in_sizes[1] / 2;    // 3200000
    const int H = in_sizes[2];        // 256

    const int* srcp = ei;
    const int* dstp = ei + E;

    const int NB  = (N + SBK - 1) >> SB_BITS;       // 49
    const int PLN = NB * SBK;                       // 100352
    const int cap = (E + NB - 1) / NB + 6144;       // ~24 sigma slack

    // workspace (u32 units): [gcur 64][dis N][y N][z N][partials RSL*PLN][packedB NB*cap]
    unsigned* W  = (unsigned*)d_ws;
    unsigned* gcur = W;
    float*    dis  = (float*)(W + 64);
    float*    y    = (float*)(W + 64 + (size_t)N);
    float*    z    = (float*)(W + 64 + (size_t)2 * N);
    unsigned* part = W + 64 + (size_t)3 * N;                  // RSL*PLN
    unsigned* packedB = part + (size_t)RSL * PLN;             // NB*cap

    hipMemsetAsync(gcur, 0, 64 * sizeof(unsigned), stream);

    const int gN = (N + 255) / 256;
    const int gA = NB * RSL;

    part_k <<<NAP, TBP, 0, stream>>>(srcp, dstp, E, cap, gcur, packedB);
    degp_k <<<gA, TBA, 0, stream>>>(packedB, gcur, cap, PLN, part);
    prep1_k<<<gN, 256, 0, stream>>>(part, x, N, PLN, dis, y);
    gaccp_k<<<gA, TBA, 0, stream>>>(packedB, gcur, y, cap, PLN, (float*)part);
    prep2_k<<<gN, 256, (size_t)3 * H * sizeof(float), stream>>>(
        (float*)part, dis, y, W1, b1, W2, z, N, H, PLN);
    gaccp_k<<<gA, TBA, 0, stream>>>(packedB, gcur, z, cap, PLN, (float*)part);
    finout_k<<<gN, 256, 0, stream>>>((float*)part, dis, z, b2, N, PLN, out);
}

// Round 6
// 189.147 us; speedup vs baseline: 2.9543x; 1.0286x over previous
//
#include <hip/hip_runtime.h>

// 2-layer GCN collapsed to scalar per-node quantities (verified R2):
//   dis = 1/sqrt(deg+1);  y = x*dis;  t[d] = sum_{e->d} y[src]
//   s = dis*(t+y);  z = dis * sum_j relu(s*W1[j]+b1[j])*W2[j]
//   out[d] = dis[d]*(sum_{e->d} z[src] + z[d]) + b2
//
// R5->R6: part_k was latency-bound (2 blocks/CU, 12 scan barriers/tile,
// 32-deep LDS atomic contention). Now: grid 1024, wave-0 shfl scan
// (4 barriers/tile), per-wave hist/rank counters (within-wave contention
// only). Aggregation: 4-way MLP batching. prep2: float4 weight reads.

#define SB_BITS 11
#define SBK     2048          // nodes per bucket
#define MAXB    64            // bucket bound (N <= 131072)
#define TBP     256           // part_k block size
#define NAPB    1024          // part_k grid
#define TPT     2048          // part_k tile (8 edges/thread)
#define NW      4             // waves per part_k block
#define RSL     16            // slices per bucket in aggregation
#define TBA     256           // aggregation block size

__device__ inline void lds_addf(float* p, float v) {
    __hip_atomic_fetch_add(p, v, __ATOMIC_RELAXED, __HIP_MEMORY_SCOPE_WORKGROUP);
}

// Partition: edges -> packedB[b*cap + pos], bucket-contiguous, coalesced.
__global__ __launch_bounds__(TBP) void part_k(
        const int* __restrict__ src, const int* __restrict__ dst, int E,
        int cap, unsigned* __restrict__ gcur, unsigned* __restrict__ packedB) {
    __shared__ unsigned sp[TPT];
    __shared__ unsigned char sbk[TPT];
    __shared__ unsigned woff[NW][MAXB];   // per-wave hist -> excl wave offset
    __shared__ unsigned cnt2[NW][MAXB];   // per-wave rank cursors
    __shared__ unsigned scn[MAXB];        // exclusive tile scan
    __shared__ unsigned gbase[MAXB];      // global claimed base
    const int t = threadIdx.x;
    const int w = t >> 6;
    const int lane = t & 63;
    int CH = (E + (int)gridDim.x - 1) / (int)gridDim.x;
    int cs = blockIdx.x * CH;
    int ce = min(cs + CH, E);
    for (int ts = cs; ts < ce; ts += TPT) {
        int tcnt = min(TPT, ce - ts);
        if (t < MAXB) {
            #pragma unroll
            for (int ww = 0; ww < NW; ww++) { woff[ww][t] = 0u; cnt2[ww][t] = 0u; }
        }
        __syncthreads();
        unsigned es[8], ed[8]; int nk = 0;
        #pragma unroll
        for (int k = 0; k < 8; k++) {
            int j = ts + t + k * TBP;
            if (j < ce) {
                es[k] = (unsigned)src[j];
                ed[k] = (unsigned)dst[j];
                atomicAdd(&woff[w][ed[k] >> SB_BITS], 1u);   // per-wave hist
                nk = k + 1;
            }
        }
        __syncthreads();
        if (t < MAXB) {   // wave 0 only: offsets, global claim, shfl scan
            unsigned h0 = woff[0][t], h1 = woff[1][t], h2 = woff[2][t], h3 = woff[3][t];
            woff[0][t] = 0u; woff[1][t] = h0; woff[2][t] = h0 + h1;
            woff[3][t] = h0 + h1 + h2;
            unsigned th = h0 + h1 + h2 + h3;
            gbase[t] = th ? atomicAdd(&gcur[t], th) : 0u;
            unsigned v = th;
            #pragma unroll
            for (int off = 1; off < 64; off <<= 1) {
                unsigned u = __shfl_up(v, off, 64);
                if (lane >= off) v += u;
            }
            scn[t] = v - th;   // exclusive bucket start within tile
        }
        __syncthreads();
        for (int k = 0; k < nk; k++) {   // rank + stage sorted
            unsigned b = ed[k] >> SB_BITS;
            unsigned r = scn[b] + woff[w][b] + atomicAdd(&cnt2[w][b], 1u);
            sp[r]  = es[k] | ((ed[k] & (SBK - 1u)) << 17);
            sbk[r] = (unsigned char)b;
        }
        __syncthreads();
        #pragma unroll
        for (int k = 0; k < 8; k++) {    // coalesced write-out
            int j2 = t + k * TBP;
            if (j2 < tcnt) {
                unsigned b = sbk[j2];
                unsigned gpos = gbase[b] + (unsigned)j2 - scn[b];
                if (gpos < (unsigned)cap)   // overflow guard
                    packedB[(size_t)b * cap + gpos] = sp[j2];
            }
        }
        __syncthreads();
    }
}

// Degree partials: grid NB*RSL, LDS u32 accumulator per bucket slice.
__global__ __launch_bounds__(TBA) void degp_k(
        const unsigned* __restrict__ packedB, const unsigned* __restrict__ gcur,
        int cap, int PLN, unsigned* __restrict__ dpart) {
    __shared__ unsigned acc[SBK];
    for (int i = threadIdx.x; i < SBK; i += TBA) acc[i] = 0u;
    __syncthreads();
    int b = blockIdx.x / RSL, r = blockIdx.x % RSL;
    unsigned cnt = min(gcur[b], (unsigned)cap);
    unsigned per = (cnt + RSL - 1) / RSL;
    unsigned s = r * per, e = min(s + per, cnt);
    const unsigned* p = packedB + (size_t)b * cap;
    unsigned j = s + threadIdx.x;
    for (; j + 3 * TBA < e; j += 4 * TBA) {
        unsigned pk0 = p[j], pk1 = p[j + TBA], pk2 = p[j + 2 * TBA], pk3 = p[j + 3 * TBA];
        atomicAdd(&acc[pk0 >> 17], 1u);
        atomicAdd(&acc[pk1 >> 17], 1u);
        atomicAdd(&acc[pk2 >> 17], 1u);
        atomicAdd(&acc[pk3 >> 17], 1u);
    }
    for (; j < e; j += TBA) atomicAdd(&acc[p[j] >> 17], 1u);
    __syncthreads();
    unsigned* o = dpart + (size_t)r * PLN + (size_t)b * SBK;
    for (int i = threadIdx.x; i < SBK; i += TBA) o[i] = acc[i];
}

// Float gather-accumulate partials (y-pass and z-pass).
__global__ __launch_bounds__(TBA) void gaccp_k(
        const unsigned* __restrict__ packedB, const unsigned* __restrict__ gcur,
        const float* __restrict__ val, int cap, int PLN,
        float* __restrict__ fpart) {
    __shared__ float acc[SBK];
    for (int i = threadIdx.x; i < SBK; i += TBA) acc[i] = 0.0f;
    __syncthreads();
    int b = blockIdx.x / RSL, r = blockIdx.x % RSL;
    unsigned cnt = min(gcur[b], (unsigned)cap);
    unsigned per = (cnt + RSL - 1) / RSL;
    unsigned s = r * per, e = min(s + per, cnt);
    const unsigned* p = packedB + (size_t)b * cap;
    unsigned j = s + threadIdx.x;
    for (; j + 3 * TBA < e; j += 4 * TBA) {
        unsigned pk0 = p[j], pk1 = p[j + TBA], pk2 = p[j + 2 * TBA], pk3 = p[j + 3 * TBA];
        float v0 = val[pk0 & 0x1FFFFu], v1 = val[pk1 & 0x1FFFFu];
        float v2 = val[pk2 & 0x1FFFFu], v3 = val[pk3 & 0x1FFFFu];
        lds_addf(&acc[pk0 >> 17], v0);
        lds_addf(&acc[pk1 >> 17], v1);
        lds_addf(&acc[pk2 >> 17], v2);
        lds_addf(&acc[pk3 >> 17], v3);
    }
    for (; j < e; j += TBA) {
        unsigned pk = p[j];
        lds_addf(&acc[pk >> 17], val[pk & 0x1FFFFu]);
    }
    __syncthreads();
    float* o = fpart + (size_t)r * PLN + (size_t)b * SBK;
    for (int i = threadIdx.x; i < SBK; i += TBA) o[i] = acc[i];
}

// deg-reduce + dis + y
__global__ void prep1_k(const unsigned* __restrict__ dpart,
                        const float* __restrict__ x, int N, int PLN,
                        float* __restrict__ dis, float* __restrict__ y) {
    int i = blockIdx.x * blockDim.x + threadIdx.x;
    if (i >= N) return;
    unsigned d = 1u;   // self loop
    #pragma unroll
    for (int r = 0; r < RSL; r++) d += dpart[(size_t)r * PLN + i];
    float rr = 1.0f / sqrtf((float)d);
    dis[i] = rr;
    y[i] = x[i] * rr;
}

// t-reduce + per-node MLP: z = dis * sum_j relu(s*W1[j]+b1[j])*W2[j]
__global__ void prep2_k(const float* __restrict__ tpart,
                        const float* __restrict__ dis,
                        const float* __restrict__ y,
                        const float* __restrict__ W1,
                        const float* __restrict__ b1,
                        const float* __restrict__ W2,
                        float* __restrict__ z, int N, int H, int PLN) {
    extern __shared__ float smem[];
    float* sW1 = smem;
    float* sb1 = smem + H;
    float* sW2 = smem + 2 * H;
    for (int j = threadIdx.x; j < H; j += blockDim.x) {
        sW1[j] = W1[j]; sb1[j] = b1[j]; sW2[j] = W2[j];
    }
    __syncthreads();
    int i = blockIdx.x * blockDim.x + threadIdx.x;
    if (i >= N) return;
    float tt = 0.0f;
    #pragma unroll
    for (int r = 0; r < RSL; r++) tt += tpart[(size_t)r * PLN + i];
    float rr = dis[i];
    float s = rr * (tt + y[i]);
    float g = 0.0f;
    const float4* w1v = (const float4*)sW1;
    const float4* b1v = (const float4*)sb1;
    const float4* w2v = (const float4*)sW2;
    #pragma unroll 4
    for (int jj = 0; jj < H / 4; jj++) {
        float4 a = w1v[jj], bb = b1v[jj], c = w2v[jj];
        float h0 = fmaf(s, a.x, bb.x); h0 = h0 > 0.0f ? h0 : 0.0f;
        float h1 = fmaf(s, a.y, bb.y); h1 = h1 > 0.0f ? h1 : 0.0f;
        float h2 = fmaf(s, a.z, bb.z); h2 = h2 > 0.0f ? h2 : 0.0f;
        float h3 = fmaf(s, a.w, bb.w); h3 = h3 > 0.0f ? h3 : 0.0f;
        g = fmaf(h0, c.x, g); g = fmaf(h1, c.y, g);
        g = fmaf(h2, c.z, g); g = fmaf(h3, c.w, g);
    }
    z[i] = g * rr;
}

// z-reduce + epilogue
__global__ void finout_k(const float* __restrict__ zpart,
                         const float* __restrict__ dis,
                         const float* __restrict__ z,
                         const float* __restrict__ b2, int N, int PLN,
                         float* __restrict__ out) {
    int i = blockIdx.x * blockDim.x + threadIdx.x;
    if (i >= N) return;
    float u = 0.0f;
    #pragma unroll
    for (int r = 0; r < RSL; r++) u += zpart[(size_t)r * PLN + i];
    out[i] = dis[i] * (u + z[i]) + b2[0];
}

extern "C" void kernel_launch(void* const* d_in, const int* in_sizes, int n_in,
                              void* d_out, int out_size, void* d_ws, size_t ws_size,
                              hipStream_t stream) {
    const float* x   = (const float*)d_in[0];
    const int*   ei  = (const int*)d_in[1];     // int32 (JAX x64-off)
    const float* W1  = (const float*)d_in[2];
    const float* b1  = (const float*)d_in[3];
    const float* W2  = (const float*)d_in[4];
    const float* b2  = (const float*)d_in[5];
    float*       out = (float*)d_out;

    const int N = in_sizes[0];        // 100000
    const int E = in_sizes[1] / 2;    // 3200000
    const int H = in_sizes[2];        // 256

    const int* srcp = ei;
    const int* dstp = ei + E;

    const int NB  = (N + SBK - 1) >> SB_BITS;       // 49
    const int PLN = NB * SBK;                       // 100352
    const int cap = (E + NB - 1) / NB + 6144;       // ~24 sigma slack

    // workspace (u32 units): [gcur 64][dis N][y N][z N][partials RSL*PLN][packedB NB*cap]
    unsigned* W  = (unsigned*)d_ws;
    unsigned* gcur = W;
    float*    dis  = (float*)(W + 64);
    float*    y    = (float*)(W + 64 + (size_t)N);
    float*    z    = (float*)(W + 64 + (size_t)2 * N);
    unsigned* part = W + 64 + (size_t)3 * N;                  // RSL*PLN
    unsigned* packedB = part + (size_t)RSL * PLN;             // NB*cap

    hipMemsetAsync(gcur, 0, 64 * sizeof(unsigned), stream);

    const int gN = (N + 255) / 256;
    const int gA = NB * RSL;

    part_k <<<NAPB, TBP, 0, stream>>>(srcp, dstp, E, cap, gcur, packedB);
    degp_k <<<gA, TBA, 0, stream>>>(packedB, gcur, cap, PLN, part);
    prep1_k<<<gN, 256, 0, stream>>>(part, x, N, PLN, dis, y);
    gaccp_k<<<gA, TBA, 0, stream>>>(packedB, gcur, y, cap, PLN, (float*)part);
    prep2_k<<<gN, 256, (size_t)3 * H * sizeof(float), stream>>>(
        (float*)part, dis, y, W1, b1, W2, z, N, H, PLN);
    gaccp_k<<<gA, TBA, 0, stream>>>(packedB, gcur, z, cap, PLN, (float*)part);
    finout_k<<<gN, 256, 0, stream>>>((float*)part, dis, z, b2, N, PLN, out);
}

// Round 7
// 173.359 us; speedup vs baseline: 3.2234x; 1.0911x over previous
//
#include <hip/hip_runtime.h>

// 2-layer GCN collapsed to scalar per-node quantities (verified R2):
//   dis = 1/sqrt(deg+1);  y = x*dis;  t[d] = sum_{e->d} y[src]
//   s = dis*(t+y);  z = dis * sum_j relu(s*W1[j]+b1[j])*W2[j]
//   out[d] = dis[d]*(sum_{e->d} z[src] + z[d]) + b2
//
// R6->R7: part_k was pinned at 48us in R5+R6 regardless of wave-side fixes.
// Invariant suspect: gcur claim atomics — 49 cursors in 196B = 6 memory-side
// 32B granules, ~12K serialized RMWs each ~= 50us. Fix: stride cursors 32B
// apart (GSTRIDE=8 u32) + TPT 2048->4096 (halves claim rounds/barriers).
// Tail: RSL 16->8 (halves partials traffic), TBA 256->512 (latency hiding).

#define SB_BITS 11
#define SBK     2048          // nodes per bucket
#define MAXB    64            // bucket bound (N <= 131072)
#define TBP     256           // part_k block size
#define NAPB    1024          // part_k grid
#define TPT     4096          // part_k tile (16 edges/thread)
#define KPT     16
#define NW      4             // waves per part_k block
#define GSTRIDE 8             // u32 stride between gcur cursors (32B granule)
#define RSL     8             // slices per bucket in aggregation
#define TBA     512           // aggregation block size

__device__ inline void lds_addf(float* p, float v) {
    __hip_atomic_fetch_add(p, v, __ATOMIC_RELAXED, __HIP_MEMORY_SCOPE_WORKGROUP);
}

// Partition: edges -> packedB[b*cap + pos], bucket-contiguous, coalesced.
__global__ __launch_bounds__(TBP) void part_k(
        const int* __restrict__ src, const int* __restrict__ dst, int E,
        int cap, unsigned* __restrict__ gcur, unsigned* __restrict__ packedB) {
    __shared__ unsigned sp[TPT];
    __shared__ unsigned char sbk[TPT];
    __shared__ unsigned woff[NW][MAXB];   // per-wave hist -> excl wave offset
    __shared__ unsigned cnt2[NW][MAXB];   // per-wave rank cursors
    __shared__ unsigned scn[MAXB];        // exclusive tile scan
    __shared__ unsigned gbase[MAXB];      // global claimed base
    const int t = threadIdx.x;
    const int w = t >> 6;
    const int lane = t & 63;
    int CH = (E + (int)gridDim.x - 1) / (int)gridDim.x;
    int cs = blockIdx.x * CH;
    int ce = min(cs + CH, E);
    for (int ts = cs; ts < ce; ts += TPT) {
        int tcnt = min(TPT, ce - ts);
        if (t < MAXB) {
            #pragma unroll
            for (int ww = 0; ww < NW; ww++) { woff[ww][t] = 0u; cnt2[ww][t] = 0u; }
        }
        __syncthreads();
        unsigned es[KPT], ed[KPT]; int nk = 0;
        #pragma unroll
        for (int k = 0; k < KPT; k++) {
            int j = ts + t + k * TBP;
            if (j < ce) {
                es[k] = (unsigned)src[j];
                ed[k] = (unsigned)dst[j];
                atomicAdd(&woff[w][ed[k] >> SB_BITS], 1u);   // per-wave hist
                nk = k + 1;
            }
        }
        __syncthreads();
        if (t < MAXB) {   // wave 0: wave offsets, strided global claim, shfl scan
            unsigned h0 = woff[0][t], h1 = woff[1][t], h2 = woff[2][t], h3 = woff[3][t];
            woff[0][t] = 0u; woff[1][t] = h0; woff[2][t] = h0 + h1;
            woff[3][t] = h0 + h1 + h2;
            unsigned th = h0 + h1 + h2 + h3;
            gbase[t] = th ? atomicAdd(&gcur[t * GSTRIDE], th) : 0u;
            unsigned v = th;
            #pragma unroll
            for (int off = 1; off < 64; off <<= 1) {
                unsigned u = __shfl_up(v, off, 64);
                if (lane >= off) v += u;
            }
            scn[t] = v - th;   // exclusive bucket start within tile
        }
        __syncthreads();
        for (int k = 0; k < nk; k++) {   // rank + stage sorted
            unsigned b = ed[k] >> SB_BITS;
            unsigned r = scn[b] + woff[w][b] + atomicAdd(&cnt2[w][b], 1u);
            sp[r]  = es[k] | ((ed[k] & (SBK - 1u)) << 17);
            sbk[r] = (unsigned char)b;
        }
        __syncthreads();
        #pragma unroll
        for (int k = 0; k < KPT; k++) {  // coalesced write-out
            int j2 = t + k * TBP;
            if (j2 < tcnt) {
                unsigned b = sbk[j2];
                unsigned gpos = gbase[b] + (unsigned)j2 - scn[b];
                if (gpos < (unsigned)cap)   // overflow guard
                    packedB[(size_t)b * cap + gpos] = sp[j2];
            }
        }
        __syncthreads();
    }
}

// Degree partials: grid NB*RSL, LDS u32 accumulator per bucket slice.
__global__ __launch_bounds__(TBA) void degp_k(
        const unsigned* __restrict__ packedB, const unsigned* __restrict__ gcur,
        int cap, int PLN, unsigned* __restrict__ dpart) {
    __shared__ unsigned acc[SBK];
    for (int i = threadIdx.x; i < SBK; i += TBA) acc[i] = 0u;
    __syncthreads();
    int b = blockIdx.x / RSL, r = blockIdx.x % RSL;
    unsigned cnt = min(gcur[b * GSTRIDE], (unsigned)cap);
    unsigned per = (cnt + RSL - 1) / RSL;
    unsigned s = r * per, e = min(s + per, cnt);
    const unsigned* p = packedB + (size_t)b * cap;
    unsigned j = s + threadIdx.x;
    for (; j + 3 * TBA < e; j += 4 * TBA) {
        unsigned pk0 = p[j], pk1 = p[j + TBA], pk2 = p[j + 2 * TBA], pk3 = p[j + 3 * TBA];
        atomicAdd(&acc[pk0 >> 17], 1u);
        atomicAdd(&acc[pk1 >> 17], 1u);
        atomicAdd(&acc[pk2 >> 17], 1u);
        atomicAdd(&acc[pk3 >> 17], 1u);
    }
    for (; j < e; j += TBA) atomicAdd(&acc[p[j] >> 17], 1u);
    __syncthreads();
    unsigned* o = dpart + (size_t)r * PLN + (size_t)b * SBK;
    for (int i = threadIdx.x; i < SBK; i += TBA) o[i] = acc[i];
}

// Float gather-accumulate partials (y-pass and z-pass).
__global__ __launch_bounds__(TBA) void gaccp_k(
        const unsigned* __restrict__ packedB, const unsigned* __restrict__ gcur,
        const float* __restrict__ val, int cap, int PLN,
        float* __restrict__ fpart) {
    __shared__ float acc[SBK];
    for (int i = threadIdx.x; i < SBK; i += TBA) acc[i] = 0.0f;
    __syncthreads();
    int b = blockIdx.x / RSL, r = blockIdx.x % RSL;
    unsigned cnt = min(gcur[b * GSTRIDE], (unsigned)cap);
    unsigned per = (cnt + RSL - 1) / RSL;
    unsigned s = r * per, e = min(s + per, cnt);
    const unsigned* p = packedB + (size_t)b * cap;
    unsigned j = s + threadIdx.x;
    for (; j + 3 * TBA < e; j += 4 * TBA) {
        unsigned pk0 = p[j], pk1 = p[j + TBA], pk2 = p[j + 2 * TBA], pk3 = p[j + 3 * TBA];
        float v0 = val[pk0 & 0x1FFFFu], v1 = val[pk1 & 0x1FFFFu];
        float v2 = val[pk2 & 0x1FFFFu], v3 = val[pk3 & 0x1FFFFu];
        lds_addf(&acc[pk0 >> 17], v0);
        lds_addf(&acc[pk1 >> 17], v1);
        lds_addf(&acc[pk2 >> 17], v2);
        lds_addf(&acc[pk3 >> 17], v3);
    }
    for (; j < e; j += TBA) {
        unsigned pk = p[j];
        lds_addf(&acc[pk >> 17], val[pk & 0x1FFFFu]);
    }
    __syncthreads();
    float* o = fpart + (size_t)r * PLN + (size_t)b * SBK;
    for (int i = threadIdx.x; i < SBK; i += TBA) o[i] = acc[i];
}

// deg-reduce + dis + y
__global__ void prep1_k(const unsigned* __restrict__ dpart,
                        const float* __restrict__ x, int N, int PLN,
                        float* __restrict__ dis, float* __restrict__ y) {
    int i = blockIdx.x * blockDim.x + threadIdx.x;
    if (i >= N) return;
    unsigned d = 1u;   // self loop
    #pragma unroll
    for (int r = 0; r < RSL; r++) d += dpart[(size_t)r * PLN + i];
    float rr = 1.0f / sqrtf((float)d);
    dis[i] = rr;
    y[i] = x[i] * rr;
}

// t-reduce + per-node MLP: z = dis * sum_j relu(s*W1[j]+b1[j])*W2[j]
__global__ void prep2_k(const float* __restrict__ tpart,
                        const float* __restrict__ dis,
                        const float* __restrict__ y,
                        const float* __restrict__ W1,
                        const float* __restrict__ b1,
                        const float* __restrict__ W2,
                        float* __restrict__ z, int N, int H, int PLN) {
    extern __shared__ float smem[];
    float* sW1 = smem;
    float* sb1 = smem + H;
    float* sW2 = smem + 2 * H;
    for (int j = threadIdx.x; j < H; j += blockDim.x) {
        sW1[j] = W1[j]; sb1[j] = b1[j]; sW2[j] = W2[j];
    }
    __syncthreads();
    int i = blockIdx.x * blockDim.x + threadIdx.x;
    if (i >= N) return;
    float tt = 0.0f;
    #pragma unroll
    for (int r = 0; r < RSL; r++) tt += tpart[(size_t)r * PLN + i];
    float rr = dis[i];
    float s = rr * (tt + y[i]);
    float g = 0.0f;
    const float4* w1v = (const float4*)sW1;
    const float4* b1v = (const float4*)sb1;
    const float4* w2v = (const float4*)sW2;
    #pragma unroll 4
    for (int jj = 0; jj < H / 4; jj++) {
        float4 a = w1v[jj], bb = b1v[jj], c = w2v[jj];
        float h0 = fmaf(s, a.x, bb.x); h0 = h0 > 0.0f ? h0 : 0.0f;
        float h1 = fmaf(s, a.y, bb.y); h1 = h1 > 0.0f ? h1 : 0.0f;
        float h2 = fmaf(s, a.z, bb.z); h2 = h2 > 0.0f ? h2 : 0.0f;
        float h3 = fmaf(s, a.w, bb.w); h3 = h3 > 0.0f ? h3 : 0.0f;
        g = fmaf(h0, c.x, g); g = fmaf(h1, c.y, g);
        g = fmaf(h2, c.z, g); g = fmaf(h3, c.w, g);
    }
    z[i] = g * rr;
}

// z-reduce + epilogue
__global__ void finout_k(const float* __restrict__ zpart,
                         const float* __restrict__ dis,
                         const float* __restrict__ z,
                         const float* __restrict__ b2, int N, int PLN,
                         float* __restrict__ out) {
    int i = blockIdx.x * blockDim.x + threadIdx.x;
    if (i >= N) return;
    float u = 0.0f;
    #pragma unroll
    for (int r = 0; r < RSL; r++) u += zpart[(size_t)r * PLN + i];
    out[i] = dis[i] * (u + z[i]) + b2[0];
}

extern "C" void kernel_launch(void* const* d_in, const int* in_sizes, int n_in,
                              void* d_out, int out_size, void* d_ws, size_t ws_size,
                              hipStream_t stream) {
    const float* x   = (const float*)d_in[0];
    const int*   ei  = (const int*)d_in[1];     // int32 (JAX x64-off)
    const float* W1  = (const float*)d_in[2];
    const float* b1  = (const float*)d_in[3];
    const float* W2  = (const float*)d_in[4];
    const float* b2  = (const float*)d_in[5];
    float*       out = (float*)d_out;

    const int N = in_sizes[0];        // 100000
    const int E = in_sizes[1] / 2;    // 3200000
    const int H = in_sizes[2];        // 256

    const int* srcp = ei;
    const int* dstp = ei + E;

    const int NB  = (N + SBK - 1) >> SB_BITS;       // 49
    const int PLN = NB * SBK;                       // 100352
    const int cap = (E + NB - 1) / NB + 6144;       // ~24 sigma slack

    // workspace (u32 units):
    // [gcur 512 (strided cursors)][dis N][y N][z N][partials RSL*PLN][packedB NB*cap]
    unsigned* W  = (unsigned*)d_ws;
    unsigned* gcur = W;
    float*    dis  = (float*)(W + 512);
    float*    y    = (float*)(W + 512 + (size_t)N);
    float*    z    = (float*)(W + 512 + (size_t)2 * N);
    unsigned* part = W + 512 + (size_t)3 * N;                 // RSL*PLN
    unsigned* packedB = part + (size_t)RSL * PLN;             // NB*cap

    hipMemsetAsync(gcur, 0, 512 * sizeof(unsigned), stream);

    const int gN = (N + 255) / 256;
    const int gA = NB * RSL;

    part_k <<<NAPB, TBP, 0, stream>>>(srcp, dstp, E, cap, gcur, packedB);
    degp_k <<<gA, TBA, 0, stream>>>(packedB, gcur, cap, PLN, part);
    prep1_k<<<gN, 256, 0, stream>>>(part, x, N, PLN, dis, y);
    gaccp_k<<<gA, TBA, 0, stream>>>(packedB, gcur, y, cap, PLN, (float*)part);
    prep2_k<<<gN, 256, (size_t)3 * H * sizeof(float), stream>>>(
        (float*)part, dis, y, W1, b1, W2, z, N, H, PLN);
    gaccp_k<<<gA, TBA, 0, stream>>>(packedB, gcur, z, cap, PLN, (float*)part);
    finout_k<<<gN, 256, 0, stream>>>((float*)part, dis, z, b2, N, PLN, out);
}

// Round 8
// 165.298 us; speedup vs baseline: 3.3806x; 1.0488x over previous
//
#include <hip/hip_runtime.h>

// 2-layer GCN collapsed to scalar per-node quantities (verified R2):
//   dis = 1/sqrt(deg+1);  y = x*dis;  t[d] = sum_{e->d} y[src]
//   s = dis*(t+y);  z = dis * sum_j relu(s*W1[j]+b1[j])*W2[j]
//   out[d] = dis[d]*(sum_{e->d} z[src] + z[d]) + b2
//
// R7->R8: residual part_k serialization = per-bucket cursor chains (782
// tile-claims/granule) + all tiles hammering the same 49 granules. Fix:
// NSET=4 independent cursor sets, each owning a private quarter-region per
// bucket -> ~195-deep chains, 4x claim parallelism. Aggregation: (b,set)
// = 196 virtual segments, RSL=8 partial rows kept; 8-way gather batching.

#define SB_BITS 11
#define SBK     2048          // nodes per bucket
#define MAXB    64            // bucket bound (N <= 131072)
#define TBP     256           // part_k block size
#define NAPB    1024          // part_k grid
#define TPT     4096          // part_k tile (16 edges/thread)
#define KPT     16
#define NW      4             // waves per part_k block
#define NSET    4             // independent cursor/region sets
#define GSTRIDE 8             // u32 stride between cursors (32B granule)
#define RSLS    2             // slices per (bucket,set) segment
#define RSL     (NSET*RSLS)   // partial rows per bucket = 8
#define TBA     512           // aggregation block size

__device__ inline void lds_addf(float* p, float v) {
    __hip_atomic_fetch_add(p, v, __ATOMIC_RELAXED, __HIP_MEMORY_SCOPE_WORKGROUP);
}

// Partition: edges -> packedB[b*cap + set*capS + pos], bucket-contiguous.
__global__ __launch_bounds__(TBP) void part_k(
        const int* __restrict__ src, const int* __restrict__ dst, int E,
        int cap, int capS, unsigned* __restrict__ gcur,
        unsigned* __restrict__ packedB) {
    __shared__ unsigned sp[TPT];
    __shared__ unsigned char sbk[TPT];
    __shared__ unsigned woff[NW][MAXB];   // per-wave hist -> excl wave offset
    __shared__ unsigned cnt2[NW][MAXB];   // per-wave rank cursors
    __shared__ unsigned scn[MAXB];        // exclusive tile scan
    __shared__ unsigned gbase[MAXB];      // global claimed base
    const int t = threadIdx.x;
    const int w = t >> 6;
    const int lane = t & 63;
    const int set = blockIdx.x & (NSET - 1);
    int CH = (E + (int)gridDim.x - 1) / (int)gridDim.x;
    int cs = blockIdx.x * CH;
    int ce = min(cs + CH, E);
    for (int ts = cs; ts < ce; ts += TPT) {
        int tcnt = min(TPT, ce - ts);
        if (t < MAXB) {
            #pragma unroll
            for (int ww = 0; ww < NW; ww++) { woff[ww][t] = 0u; cnt2[ww][t] = 0u; }
        }
        __syncthreads();
        unsigned es[KPT], ed[KPT]; int nk = 0;
        #pragma unroll
        for (int k = 0; k < KPT; k++) {
            int j = ts + t + k * TBP;
            if (j < ce) {
                es[k] = (unsigned)src[j];
                ed[k] = (unsigned)dst[j];
                atomicAdd(&woff[w][ed[k] >> SB_BITS], 1u);   // per-wave hist
                nk = k + 1;
            }
        }
        __syncthreads();
        if (t < MAXB) {   // wave 0: wave offsets, set-strided claim, shfl scan
            unsigned h0 = woff[0][t], h1 = woff[1][t], h2 = woff[2][t], h3 = woff[3][t];
            woff[0][t] = 0u; woff[1][t] = h0; woff[2][t] = h0 + h1;
            woff[3][t] = h0 + h1 + h2;
            unsigned th = h0 + h1 + h2 + h3;
            gbase[t] = th ? atomicAdd(&gcur[(t * NSET + set) * GSTRIDE], th) : 0u;
            unsigned v = th;
            #pragma unroll
            for (int off = 1; off < 64; off <<= 1) {
                unsigned u = __shfl_up(v, off, 64);
                if (lane >= off) v += u;
            }
            scn[t] = v - th;   // exclusive bucket start within tile
        }
        __syncthreads();
        for (int k = 0; k < nk; k++) {   // rank + stage sorted
            unsigned b = ed[k] >> SB_BITS;
            unsigned r = scn[b] + woff[w][b] + atomicAdd(&cnt2[w][b], 1u);
            sp[r]  = es[k] | ((ed[k] & (SBK - 1u)) << 17);
            sbk[r] = (unsigned char)b;
        }
        __syncthreads();
        #pragma unroll
        for (int k = 0; k < KPT; k++) {  // coalesced write-out
            int j2 = t + k * TBP;
            if (j2 < tcnt) {
                unsigned b = sbk[j2];
                unsigned gpos = gbase[b] + (unsigned)j2 - scn[b];
                if (gpos < (unsigned)capS)   // overflow guard (per-set region)
                    packedB[(size_t)b * cap + (size_t)set * capS + gpos] = sp[j2];
            }
        }
        __syncthreads();
    }
}

// Degree partials: grid NB*NSET*RSLS. LDS u32 accumulator per segment slice.
__global__ __launch_bounds__(TBA) void degp_k(
        const unsigned* __restrict__ packedB, const unsigned* __restrict__ gcur,
        int cap, int capS, int PLN, unsigned* __restrict__ dpart) {
    __shared__ unsigned acc[SBK];
    for (int i = threadIdx.x; i < SBK; i += TBA) acc[i] = 0u;
    __syncthreads();
    int vb = blockIdx.x / RSLS, rs = blockIdx.x % RSLS;
    int b = vb >> 2, set = vb & 3;
    unsigned cnt = min(gcur[(b * NSET + set) * GSTRIDE], (unsigned)capS);
    unsigned per = (cnt + RSLS - 1) / RSLS;
    unsigned s = rs * per, e = min(s + per, cnt);
    const unsigned* p = packedB + (size_t)b * cap + (size_t)set * capS;
    unsigned j = s + threadIdx.x;
    for (; j + 7 * TBA < e; j += 8 * TBA) {
        unsigned pk0 = p[j],           pk1 = p[j + TBA],     pk2 = p[j + 2 * TBA], pk3 = p[j + 3 * TBA];
        unsigned pk4 = p[j + 4 * TBA], pk5 = p[j + 5 * TBA], pk6 = p[j + 6 * TBA], pk7 = p[j + 7 * TBA];
        atomicAdd(&acc[pk0 >> 17], 1u); atomicAdd(&acc[pk1 >> 17], 1u);
        atomicAdd(&acc[pk2 >> 17], 1u); atomicAdd(&acc[pk3 >> 17], 1u);
        atomicAdd(&acc[pk4 >> 17], 1u); atomicAdd(&acc[pk5 >> 17], 1u);
        atomicAdd(&acc[pk6 >> 17], 1u); atomicAdd(&acc[pk7 >> 17], 1u);
    }
    for (; j < e; j += TBA) atomicAdd(&acc[p[j] >> 17], 1u);
    __syncthreads();
    int r = set * RSLS + rs;
    unsigned* o = dpart + (size_t)r * PLN + (size_t)b * SBK;
    for (int i = threadIdx.x; i < SBK; i += TBA) o[i] = acc[i];
}

// Float gather-accumulate partials (y-pass and z-pass).
__global__ __launch_bounds__(TBA) void gaccp_k(
        const unsigned* __restrict__ packedB, const unsigned* __restrict__ gcur,
        const float* __restrict__ val, int cap, int capS, int PLN,
        float* __restrict__ fpart) {
    __shared__ float acc[SBK];
    for (int i = threadIdx.x; i < SBK; i += TBA) acc[i] = 0.0f;
    __syncthreads();
    int vb = blockIdx.x / RSLS, rs = blockIdx.x % RSLS;
    int b = vb >> 2, set = vb & 3;
    unsigned cnt = min(gcur[(b * NSET + set) * GSTRIDE], (unsigned)capS);
    unsigned per = (cnt + RSLS - 1) / RSLS;
    unsigned s = rs * per, e = min(s + per, cnt);
    const unsigned* p = packedB + (size_t)b * cap + (size_t)set * capS;
    unsigned j = s + threadIdx.x;
    for (; j + 7 * TBA < e; j += 8 * TBA) {
        unsigned pk0 = p[j],           pk1 = p[j + TBA],     pk2 = p[j + 2 * TBA], pk3 = p[j + 3 * TBA];
        unsigned pk4 = p[j + 4 * TBA], pk5 = p[j + 5 * TBA], pk6 = p[j + 6 * TBA], pk7 = p[j + 7 * TBA];
        float v0 = val[pk0 & 0x1FFFFu], v1 = val[pk1 & 0x1FFFFu];
        float v2 = val[pk2 & 0x1FFFFu], v3 = val[pk3 & 0x1FFFFu];
        float v4 = val[pk4 & 0x1FFFFu], v5 = val[pk5 & 0x1FFFFu];
        float v6 = val[pk6 & 0x1FFFFu], v7 = val[pk7 & 0x1FFFFu];
        lds_addf(&acc[pk0 >> 17], v0); lds_addf(&acc[pk1 >> 17], v1);
        lds_addf(&acc[pk2 >> 17], v2); lds_addf(&acc[pk3 >> 17], v3);
        lds_addf(&acc[pk4 >> 17], v4); lds_addf(&acc[pk5 >> 17], v5);
        lds_addf(&acc[pk6 >> 17], v6); lds_addf(&acc[pk7 >> 17], v7);
    }
    for (; j < e; j += TBA) {
        unsigned pk = p[j];
        lds_addf(&acc[pk >> 17], val[pk & 0x1FFFFu]);
    }
    __syncthreads();
    int r = set * RSLS + rs;
    float* o = fpart + (size_t)r * PLN + (size_t)b * SBK;
    for (int i = threadIdx.x; i < SBK; i += TBA) o[i] = acc[i];
}

// deg-reduce + dis + y
__global__ void prep1_k(const unsigned* __restrict__ dpart,
                        const float* __restrict__ x, int N, int PLN,
                        float* __restrict__ dis, float* __restrict__ y) {
    int i = blockIdx.x * blockDim.x + threadIdx.x;
    if (i >= N) return;
    unsigned d = 1u;   // self loop
    #pragma unroll
    for (int r = 0; r < RSL; r++) d += dpart[(size_t)r * PLN + i];
    float rr = 1.0f / sqrtf((float)d);
    dis[i] = rr;
    y[i] = x[i] * rr;
}

// t-reduce + per-node MLP: z = dis * sum_j relu(s*W1[j]+b1[j])*W2[j]
__global__ void prep2_k(const float* __restrict__ tpart,
                        const float* __restrict__ dis,
                        const float* __restrict__ y,
                        const float* __restrict__ W1,
                        const float* __restrict__ b1,
                        const float* __restrict__ W2,
                        float* __restrict__ z, int N, int H, int PLN) {
    extern __shared__ float smem[];
    float* sW1 = smem;
    float* sb1 = smem + H;
    float* sW2 = smem + 2 * H;
    for (int j = threadIdx.x; j < H; j += blockDim.x) {
        sW1[j] = W1[j]; sb1[j] = b1[j]; sW2[j] = W2[j];
    }
    __syncthreads();
    int i = blockIdx.x * blockDim.x + threadIdx.x;
    if (i >= N) return;
    float tt = 0.0f;
    #pragma unroll
    for (int r = 0; r < RSL; r++) tt += tpart[(size_t)r * PLN + i];
    float rr = dis[i];
    float s = rr * (tt + y[i]);
    float g = 0.0f;
    const float4* w1v = (const float4*)sW1;
    const float4* b1v = (const float4*)sb1;
    const float4* w2v = (const float4*)sW2;
    #pragma unroll 8
    for (int jj = 0; jj < H / 4; jj++) {
        float4 a = w1v[jj], bb = b1v[jj], c = w2v[jj];
        float h0 = fmaf(s, a.x, bb.x); h0 = h0 > 0.0f ? h0 : 0.0f;
        float h1 = fmaf(s, a.y, bb.y); h1 = h1 > 0.0f ? h1 : 0.0f;
        float h2 = fmaf(s, a.z, bb.z); h2 = h2 > 0.0f ? h2 : 0.0f;
        float h3 = fmaf(s, a.w, bb.w); h3 = h3 > 0.0f ? h3 : 0.0f;
        g = fmaf(h0, c.x, g); g = fmaf(h1, c.y, g);
        g = fmaf(h2, c.z, g); g = fmaf(h3, c.w, g);
    }
    z[i] = g * rr;
}

// z-reduce + epilogue
__global__ void finout_k(const float* __restrict__ zpart,
                         const float* __restrict__ dis,
                         const float* __restrict__ z,
                         const float* __restrict__ b2, int N, int PLN,
                         float* __restrict__ out) {
    int i = blockIdx.x * blockDim.x + threadIdx.x;
    if (i >= N) return;
    float u = 0.0f;
    #pragma unroll
    for (int r = 0; r < RSL; r++) u += zpart[(size_t)r * PLN + i];
    out[i] = dis[i] * (u + z[i]) + b2[0];
}

extern "C" void kernel_launch(void* const* d_in, const int* in_sizes, int n_in,
                              void* d_out, int out_size, void* d_ws, size_t ws_size,
                              hipStream_t stream) {
    const float* x   = (const float*)d_in[0];
    const int*   ei  = (const int*)d_in[1];     // int32 (JAX x64-off)
    const float* W1  = (const float*)d_in[2];
    const float* b1  = (const float*)d_in[3];
    const float* W2  = (const float*)d_in[4];
    const float* b2  = (const float*)d_in[5];
    float*       out = (float*)d_out;

    const int N = in_sizes[0];        // 100000
    const int E = in_sizes[1] / 2;    // 3200000
    const int H = in_sizes[2];        // 256

    const int* srcp = ei;
    const int* dstp = ei + E;

    const int NB   = (N + SBK - 1) >> SB_BITS;           // 49
    const int PLN  = NB * SBK;                           // 100352
    const int capS = E / (NB * NSET) + 3584;             // per-set slack ~28 sigma
    const int cap  = capS * NSET;

    // workspace (u32 units):
    // [gcur 2048 (set-strided cursors)][dis N][y N][z N][partials RSL*PLN][packedB NB*cap]
    unsigned* W  = (unsigned*)d_ws;
    unsigned* gcur = W;
    float*    dis  = (float*)(W + 2048);
    float*    y    = (float*)(W + 2048 + (size_t)N);
    float*    z    = (float*)(W + 2048 + (size_t)2 * N);
    unsigned* part = W + 2048 + (size_t)3 * N;                // RSL*PLN
    unsigned* packedB = part + (size_t)RSL * PLN;             // NB*cap

    hipMemsetAsync(gcur, 0, 2048 * sizeof(unsigned), stream);

    const int gN = (N + 255) / 256;
    const int gA = NB * NSET * RSLS;

    part_k <<<NAPB, TBP, 0, stream>>>(srcp, dstp, E, cap, capS, gcur, packedB);
    degp_k <<<gA, TBA, 0, stream>>>(packedB, gcur, cap, capS, PLN, part);
    prep1_k<<<gN, 256, 0, stream>>>(part, x, N, PLN, dis, y);
    gaccp_k<<<gA, TBA, 0, stream>>>(packedB, gcur, y, cap, capS, PLN, (float*)part);
    prep2_k<<<gN, 256, (size_t)3 * H * sizeof(float), stream>>>(
        (float*)part, dis, y, W1, b1, W2, z, N, H, PLN);
    gaccp_k<<<gA, TBA, 0, stream>>>(packedB, gcur, z, cap, capS, PLN, (float*)part);
    finout_k<<<gN, 256, 0, stream>>>((float*)part, dis, z, b2, N, PLN, out);
}